// Round 12
// baseline (274.494 us; speedup 1.0000x reference)
//
#include <hip/hip_runtime.h>
#include <stdint.h>

#define D_MODEL 1024
#define NH 16
#define DH 64
#define TSEQ 2048
#define BATCH 4
#define MTOT (BATCH*TSEQ)
#define NQ (MTOT*D_MODEL)      // elements in Q/K/VT/AO and in x
#define WSZ (D_MODEL*D_MODEL)  // elements in each weight matrix
// SCALE * log2(e), pre-folded into Q at the qkv epilogue
#define QSCALE 0.18033688f

typedef __attribute__((ext_vector_type(8))) short bf16x8;
typedef __attribute__((ext_vector_type(8))) unsigned short u16x8;
typedef __attribute__((ext_vector_type(4))) float f32x4;
typedef __attribute__((ext_vector_type(2))) float f32x2;
typedef unsigned short u16;
typedef unsigned int u32;

__device__ __forceinline__ void gl_lds16(const void* g, void* l) {
  __builtin_amdgcn_global_load_lds(
      (__attribute__((address_space(1))) void*)g,
      (__attribute__((address_space(3))) void*)l, 16, 0, 0);
}
__device__ __forceinline__ u16 f2bf(float f) {
  u32 u = __builtin_bit_cast(u32, f);
  u = u + 0x7fffu + ((u >> 16) & 1u);
  return (u16)(u >> 16);
}
__device__ __forceinline__ float bf2f(u16 b) {
  u32 u = ((u32)b) << 16;
  return __builtin_bit_cast(float, u);
}

// ---------------------------------------------------------------------------
// Fused raw exp2 + bf16 pack, hazards controlled IN-ASM (round-4 verified).
// Round-2 lesson: TRANS results consumed by a SEPARATE inline-asm within the
// hazard window gave wrong numerics; one asm block with 4 back-to-back exps
// + s_nop 1 before the packs is safe.
// ROUND-9 lesson: K/V LDS swizzle cut SQ_LDS_BANK_CONFLICT 40% but cost 4%
// time — conflicts are NOT on this schedule's critical path.
// ROUND-11: lsum-via-MFMA verified (flash 93.3 -> 90.5, MfmaUtil 30 -> 35).
// ROUND-12: qkv tile 128 -> 256 rows (512 threads): staging bytes per MFMA
// 170 -> 104 (qkv is staging-BW-bound: 137 B/cyc/CU demand vs ~64 B/cyc
// path). Occupancy unchanged (2 waves/SIMD); barrier structure unchanged
// (r8 lesson: drain FREQUENCY hurts; this changes bytes/MFMA instead).
// ---------------------------------------------------------------------------
__device__ __forceinline__ void exp2pk4(const f32x4 s, float& e0, float& e1,
                                        float& e2, float& e3, u32& pk01,
                                        u32& pk23) {
  asm("v_exp_f32 %0, %6\n\t"
      "v_exp_f32 %1, %7\n\t"
      "v_exp_f32 %2, %8\n\t"
      "v_exp_f32 %3, %9\n\t"
      "s_nop 1\n\t"
      "v_cvt_pk_bf16_f32 %4, %0, %1\n\t"
      "v_cvt_pk_bf16_f32 %5, %2, %3"
      : "=&v"(e0), "=&v"(e1), "=&v"(e2), "=&v"(e3), "=&v"(pk01), "=&v"(pk23)
      : "v"(s[0]), "v"(s[1]), "v"(s[2]), "v"(s[3]));
}

// ---------------------------------------------------------------------------
// Kernel 0: input dtype detection (1 = bf16, 0 = fp32).
// ---------------------------------------------------------------------------
__global__ __launch_bounds__(256) void detect_dtype(
    const u32* __restrict__ wq_raw, int* __restrict__ flag)
{
  __shared__ int cnt;
  if (threadIdx.x == 0) cnt = 0;
  __syncthreads();
  int c = 0;
  for (int i = threadIdx.x; i < 2048; i += 256) {
    const u32 e = (wq_raw[i] >> 7) & 0xFFu;
    if (e >= 90u && e <= 126u) ++c;
  }
  atomicAdd(&cnt, c);
  __syncthreads();
  if (threadIdx.x == 0) *flag = (cnt > 1024) ? 1 : 0;
}

// ---------------------------------------------------------------------------
// Kernel 0b: convert inputs to bf16 — fp32 path ONLY (flag=1 early-exits;
// consumers read raw pointers directly).
// ---------------------------------------------------------------------------
__global__ __launch_bounds__(256) void convert_inputs(
    const void* __restrict__ x, const void* __restrict__ wq,
    const void* __restrict__ wk, const void* __restrict__ wv,
    const void* __restrict__ wo,
    u16* __restrict__ xb, u16* __restrict__ wqb, u16* __restrict__ wkb,
    u16* __restrict__ wvb, u16* __restrict__ wob,
    const int* __restrict__ flag_p)
{
  if (*flag_p) return;  // bf16 inputs: consumers read raw pointers directly
  const int seg = blockIdx.y;
  const void* src; u16* dst; int n;
  switch (seg) {
    case 0:  src = x;  dst = xb;  n = NQ;  break;
    case 1:  src = wq; dst = wqb; n = WSZ; break;
    case 2:  src = wk; dst = wkb; n = WSZ; break;
    case 3:  src = wv; dst = wvb; n = WSZ; break;
    default: src = wo; dst = wob; n = WSZ; break;
  }
  const int idx = (blockIdx.x * 256 + threadIdx.x) * 8;
  if (idx >= n) return;
  const float4 f0 = *(const float4*)((const float*)src + idx);
  const float4 f1 = *(const float4*)((const float*)src + idx + 4);
  union { u16 s[8]; u16x8 v; } u;
  u.s[0] = f2bf(f0.x); u.s[1] = f2bf(f0.y); u.s[2] = f2bf(f0.z); u.s[3] = f2bf(f0.w);
  u.s[4] = f2bf(f1.x); u.s[5] = f2bf(f1.y); u.s[6] = f2bf(f1.z); u.s[7] = f2bf(f1.w);
  *(u16x8*)(dst + idx) = u.v;
}

// ---------------------------------------------------------------------------
// Kernel 1: FUSED QKV projection — ROUND-12: 256x128 tile, 512 threads
// (8 waves, 2M x 2N wave grid, 64x64 per-wave tiles). One K-loop stages the
// 256-row A-tile (X) ONCE plus three 128-row B-tiles; 768 wave-MFMA per
// barrier-pair on 80 KB staged (104 B/MFMA vs 170 at the 128-tile).
// LDS 80 KB -> 1 block/CU x 8 waves = 2 waves/SIMD (same as before).
// K-output via swapped operands mfma(bk, af) -> D[d][t] for 8B stores.
// Outputs: Q^T [B,H,64,T] (pre-scaled), K [B,H,T,64], V^T [B,H,64,T].
// ---------------------------------------------------------------------------
__global__ __launch_bounds__(512, 2) void qkv_gemm(
    const int* __restrict__ flag_p, const u16* __restrict__ x_raw,
    u16* __restrict__ dout,
    const u16* __restrict__ Wq, const u16* __restrict__ Wk,
    const u16* __restrict__ Wv,
    const void* __restrict__ wq_r, const void* __restrict__ wk_r,
    const void* __restrict__ wv_r,
    u16* __restrict__ Ko, u16* __restrict__ VTo)
{
  __shared__ __align__(16) u16 As [2][256 * 32];  // [k-half][256 rows][32 k]
  __shared__ __align__(16) u16 Bqs[2][128 * 32];
  __shared__ __align__(16) u16 Bks[2][128 * 32];
  __shared__ __align__(16) u16 Bvs[2][128 * 32];
  const int flag = *flag_p;
  const u16* __restrict__ X  = flag ? x_raw : dout;  // converted x in dout low
  u16* __restrict__ QTo = flag ? dout : dout + NQ;
  const u16* __restrict__ WQ = flag ? (const u16*)wq_r : Wq;
  const u16* __restrict__ WK = flag ? (const u16*)wk_r : Wk;
  const u16* __restrict__ WV = flag ? (const u16*)wv_r : Wv;
  const int t = threadIdx.x;
  const int m0 = blockIdx.x * 256;
  const int n0 = blockIdx.y * 128;
  const int wave = t >> 6, lane = t & 63;
  const int wm = (wave >> 1) * 64, wn = (wave & 1) * 64;
  const int lr = lane & 15, g = lane >> 4, kg = g * 8;

  // staging: 512 threads, row = t>>2 (0..127), 16B chunk = t&3; A needs a
  // second round for rows 128..255. All dests lane-linear (dest = t*8).
  const int srow = t >> 2, skc = (t & 3) * 8;
  const u16* a0  = X  + (size_t)(m0 + srow) * D_MODEL + skc;
  const u16* a1  = X  + (size_t)(m0 + 128 + srow) * D_MODEL + skc;
  const u16* q0p = WQ + (size_t)(n0 + srow) * D_MODEL + skc;
  const u16* k0p = WK + (size_t)(n0 + srow) * D_MODEL + skc;
  const u16* v0p = WV + (size_t)(n0 + srow) * D_MODEL + skc;

  f32x4 accq[4][4] = {};  // [i=m][j=n]
  f32x4 acck[4][4] = {};  // [j=n][i=m]  (swapped-operand output D[d][t])
  f32x4 accv[4][4] = {};  // [i=m][j=n]

  for (int kt = 0; kt < D_MODEL / 64; ++kt) {
    gl_lds16(a0,       &As[0][t * 8]);          // rows 0..127,  k-half 0
    gl_lds16(a1,       &As[0][4096 + t * 8]);   // rows 128..255, k-half 0
    gl_lds16(a0 + 32,  &As[1][t * 8]);          // rows 0..127,  k-half 1
    gl_lds16(a1 + 32,  &As[1][4096 + t * 8]);   // rows 128..255, k-half 1
    gl_lds16(q0p,      &Bqs[0][t * 8]);
    gl_lds16(q0p + 32, &Bqs[1][t * 8]);
    gl_lds16(k0p,      &Bks[0][t * 8]);
    gl_lds16(k0p + 32, &Bks[1][t * 8]);
    gl_lds16(v0p,      &Bvs[0][t * 8]);
    gl_lds16(v0p + 32, &Bvs[1][t * 8]);
    a0 += 64; a1 += 64; q0p += 64; k0p += 64; v0p += 64;
    __syncthreads();
#pragma unroll
    for (int h = 0; h < 2; ++h) {
      bf16x8 af[4], bfr[4];
#pragma unroll
      for (int i = 0; i < 4; ++i)
        af[i] = *(const bf16x8*)&As[h][(wm + i * 16 + lr) * 32 + kg];
      // Q
#pragma unroll
      for (int j = 0; j < 4; ++j)
        bfr[j] = *(const bf16x8*)&Bqs[h][(wn + j * 16 + lr) * 32 + kg];
#pragma unroll
      for (int i = 0; i < 4; ++i)
#pragma unroll
        for (int j = 0; j < 4; ++j)
          accq[i][j] = __builtin_amdgcn_mfma_f32_16x16x32_bf16(af[i], bfr[j], accq[i][j], 0, 0, 0);
      // K (swapped: A = W-fragment -> rows = d, cols = t)
#pragma unroll
      for (int j = 0; j < 4; ++j)
        bfr[j] = *(const bf16x8*)&Bks[h][(wn + j * 16 + lr) * 32 + kg];
#pragma unroll
      for (int j = 0; j < 4; ++j)
#pragma unroll
        for (int i = 0; i < 4; ++i)
          acck[j][i] = __builtin_amdgcn_mfma_f32_16x16x32_bf16(bfr[j], af[i], acck[j][i], 0, 0, 0);
      // V
#pragma unroll
      for (int j = 0; j < 4; ++j)
        bfr[j] = *(const bf16x8*)&Bvs[h][(wn + j * 16 + lr) * 32 + kg];
#pragma unroll
      for (int i = 0; i < 4; ++i)
#pragma unroll
        for (int j = 0; j < 4; ++j)
          accv[i][j] = __builtin_amdgcn_mfma_f32_16x16x32_bf16(af[i], bfr[j], accv[i][j], 0, 0, 0);
    }
    __syncthreads();
  }

  // C/D layout: col = lane&15, row = (lane>>4)*4 + reg
  const int bidx = m0 >> 11;  // 256-row tile never crosses a 2048-row batch
  // --- Q^T (scaled) and V^T: [B,H,64,T], vectorized 8B stores along t ---
#pragma unroll
  for (int zz = 0; zz < 2; ++zz) {
    u16* O = zz ? VTo : QTo;
    const float sc = zz ? 1.0f : QSCALE;
#pragma unroll
    for (int i = 0; i < 4; ++i) {
      const int rowg = m0 + wm + i * 16 + (g << 2);
      const int tq = rowg & (TSEQ - 1);  // multiple of 4 -> 8B aligned
#pragma unroll
      for (int j = 0; j < 4; ++j) {
        const int colg = n0 + wn + j * 16 + lr;
        const int h = colg >> 6, d = colg & 63;
        const f32x4 a = zz ? accv[i][j] : accq[i][j];
        union { u16 s[4]; uint2 v; } u;
#pragma unroll
        for (int r = 0; r < 4; ++r) u.s[r] = f2bf(a[r] * sc);
        *(uint2*)&O[((size_t)(bidx * NH + h) * DH + d) * TSEQ + tq] = u.v;
      }
    }
  }
  // --- K: [B,H,T,64]. Swapped output D[d][t]: col=lr -> t, row=g*4+r -> d.
  //     reg r walks d => one 8B store per (j,i). ---
#pragma unroll
  for (int j = 0; j < 4; ++j) {
    const int dg = n0 + wn + j * 16 + (g << 2);  // d-global base (r adds 0..3)
    const int hh = dg >> 6, d0 = dg & 63;        // head fixed over r
#pragma unroll
    for (int i = 0; i < 4; ++i) {
      const int tg = m0 + wm + i * 16 + lr;
      const int tq = tg & (TSEQ - 1);
      union { u16 s[4]; uint2 v; } u;
#pragma unroll
      for (int r = 0; r < 4; ++r) u.s[r] = f2bf(acck[j][i][r]);
      *(uint2*)&Ko[((size_t)(bidx * NH + hh) * TSEQ + tq) * DH + d0] = u.v;
    }
  }
}

// ---------------------------------------------------------------------------
// Kernel 2: flash attention — round-11 version (green, 90.5 us, MfmaUtil 35).
// Round-6 structure + lsum-via-MFMA (denominator = row-sum of the SAME
// rounded bf16 P via mfma(P_frag, ones); no Ls / shuffles / final barrier).
// ---------------------------------------------------------------------------
__global__ __launch_bounds__(256) void flash_attn(
    const int* __restrict__ flag_p, const u16* __restrict__ dout,
    const u16* __restrict__ K, const u16* __restrict__ VT,
    u16* __restrict__ AO)
{
  __shared__ __align__(16) u16 Ks[2][2 * 64 * 32];  // [buf][half][64 keys][32 d]
  __shared__ __align__(16) u16 Vs[2][2 * 64 * 32];  // [buf][half][64 d][32 keys]
  __shared__ __align__(16) u16 Ps[4 * 64 * 72];     // per-wave [64 q][64+8 keys]
  const int flag = *flag_p;
  const u16* __restrict__ QT = flag ? dout : dout + NQ;
  const int t = threadIdx.x;
  const int wave = t >> 6, lane = t & 63;
  const int lr = lane & 15, g = lane >> 4, kg = g * 8;
  const int bh = blockIdx.x;          // fastest grid dim -> XCD = bh % 8
  const int q0 = blockIdx.y * 256;
  const u16* __restrict__ QTh = QT + (size_t)bh * DH * TSEQ;  // [64 d][T]
  const u16* __restrict__ Kh = K + (size_t)bh * TSEQ * DH;
  const u16* __restrict__ Vh = VT + (size_t)bh * DH * TSEQ;

  // 8 Q B-fragments per wave: q-sets s=0..3 (16 q each), d-halves 0/1.
  const int qi = q0 + wave * 64 + lr;
  bf16x8 qf[8];
#pragma unroll
  for (int s = 0; s < 4; ++s) {
    union { u16 v[8]; bf16x8 b; } u0, u1;
#pragma unroll
    for (int j = 0; j < 8; ++j) {
      u0.v[j] = QTh[(size_t)(kg + j) * TSEQ + qi + s * 16];
      u1.v[j] = QTh[(size_t)(32 + kg + j) * TSEQ + qi + s * 16];
    }
    qf[s * 2] = u0.b; qf[s * 2 + 1] = u1.b;
  }

  // ones fragment for the lsum MFMA (bf16 1.0 = 0x3F80)
  union { u32 w[4]; bf16x8 b; } onesu;
  onesu.w[0] = onesu.w[1] = onesu.w[2] = onesu.w[3] = 0x3F803F80u;
  const bf16x8 vones = onesu.b;

  f32x4 acc[4][4] = {};                 // [set][dn]
  f32x4 accl[4] = {};                   // [set] row-sums of P (lsum)

  const int srow = t >> 2, skc = (t & 3) * 8;
  const u16* kb = Kh + (size_t)srow * DH + skc;
  const u16* vb = Vh + (size_t)srow * TSEQ + skc;
  u16* const pw = &Ps[wave * 64 * 72];  // q-set s at rows s*16..s*16+15

  // prologue: prefetch tile 0 into buffer 0
  gl_lds16(kb,      &Ks[0][t * 8]);          // keys, d 0..31
  gl_lds16(kb + 32, &Ks[0][(t + 256) * 8]);  // keys, d 32..63
  gl_lds16(vb,      &Vs[0][t * 8]);          // [d][keys 0..31]
  gl_lds16(vb + 32, &Vs[0][(t + 256) * 8]);  // [d][keys 32..63]
  kb += 64 * DH; vb += 64;

  int cur = 0;
  for (int j0 = 0; j0 < TSEQ; j0 += 64) {
    // single barrier per tile: drains cur-buf loads (issued a full tile ago)
    // and guarantees everyone is done reading buf^1 before we overwrite it.
    __syncthreads();
    if (j0 + 64 < TSEQ) {
      gl_lds16(kb,      &Ks[cur ^ 1][t * 8]);
      gl_lds16(kb + 32, &Ks[cur ^ 1][(t + 256) * 8]);
      gl_lds16(vb,      &Vs[cur ^ 1][t * 8]);
      gl_lds16(vb + 32, &Vs[cur ^ 1][(t + 256) * 8]);
      kb += 64 * DH; vb += 64;
    }
    const u16* __restrict__ Kc = Ks[cur];
    const u16* __restrict__ Vc = Vs[cur];

    // --- QK key-rows 0..31 (jn = 0,1) ---
#pragma unroll
    for (int jn = 0; jn < 2; ++jn) {
      const bf16x8 kf0 = *(const bf16x8*)&Kc[(jn * 16 + lr) * 32 + kg];
      const bf16x8 kf1 = *(const bf16x8*)&Kc[2048 + (jn * 16 + lr) * 32 + kg];
#pragma unroll
      for (int s = 0; s < 4; ++s) {
        f32x4 sS = {};
        sS = __builtin_amdgcn_mfma_f32_16x16x32_bf16(kf0, qf[s * 2],     sS, 0, 0, 0);
        sS = __builtin_amdgcn_mfma_f32_16x16x32_bf16(kf1, qf[s * 2 + 1], sS, 0, 0, 0);
        float e0, e1, e2, e3;
        uint2 w;
        exp2pk4(sS, e0, e1, e2, e3, w.x, w.y);
        *(uint2*)&pw[s * 16 * 72 + lr * 72 + jn * 16 + g * 4] = w;
      }
    }

    // pf0 (keys 0..31) issued now: in-order DS -> completes after the jn0/1
    // writes (same region) but does NOT wait on the jn2/3 writes below.
    bf16x8 pf0[4];
#pragma unroll
    for (int s = 0; s < 4; ++s)
      pf0[s] = *(const bf16x8*)&pw[s * 16 * 72 + lr * 72 + kg];

    // --- QK key-rows 32..63 (jn = 2,3): VALU here covers pf0 DS latency ---
#pragma unroll
    for (int jn = 2; jn < 4; ++jn) {
      const bf16x8 kf0 = *(const bf16x8*)&Kc[(jn * 16 + lr) * 32 + kg];
      const bf16x8 kf1 = *(const bf16x8*)&Kc[2048 + (jn * 16 + lr) * 32 + kg];
#pragma unroll
      for (int s = 0; s < 4; ++s) {
        f32x4 sS = {};
        sS = __builtin_amdgcn_mfma_f32_16x16x32_bf16(kf0, qf[s * 2],     sS, 0, 0, 0);
        sS = __builtin_amdgcn_mfma_f32_16x16x32_bf16(kf1, qf[s * 2 + 1], sS, 0, 0, 0);
        float e0, e1, e2, e3;
        uint2 w;
        exp2pk4(sS, e0, e1, e2, e3, w.x, w.y);
        *(uint2*)&pw[s * 16 * 72 + lr * 72 + jn * 16 + g * 4] = w;
      }
    }

    // --- PV key-half 0 (+ lsum row-sum via ones-MFMA) ---
#pragma unroll
    for (int dn = 0; dn < 4; ++dn) {
      const bf16x8 vf0 = *(const bf16x8*)&Vc[(dn * 16 + lr) * 32 + kg];
#pragma unroll
      for (int s = 0; s < 4; ++s)
        acc[s][dn] = __builtin_amdgcn_mfma_f32_16x16x32_bf16(pf0[s], vf0, acc[s][dn], 0, 0, 0);
    }
#pragma unroll
    for (int s = 0; s < 4; ++s)
      accl[s] = __builtin_amdgcn_mfma_f32_16x16x32_bf16(pf0[s], vones, accl[s], 0, 0, 0);

    // pf1 (keys 32..63), then PV key-half 1 (+ lsum)
    bf16x8 pf1[4];
#pragma unroll
    for (int s = 0; s < 4; ++s)
      pf1[s] = *(const bf16x8*)&pw[s * 16 * 72 + lr * 72 + 32 + kg];
#pragma unroll
    for (int dn = 0; dn < 4; ++dn) {
      const bf16x8 vf1 = *(const bf16x8*)&Vc[2048 + (dn * 16 + lr) * 32 + kg];
#pragma unroll
      for (int s = 0; s < 4; ++s)
        acc[s][dn] = __builtin_amdgcn_mfma_f32_16x16x32_bf16(pf1[s], vf1, acc[s][dn], 0, 0, 0);
    }
#pragma unroll
    for (int s = 0; s < 4; ++s)
      accl[s] = __builtin_amdgcn_mfma_f32_16x16x32_bf16(pf1[s], vones, accl[s], 0, 0, 0);
    cur ^= 1;
  }

  // Epilogue: accl[s][r] holds lsum for q-row g*4+r of set s (all 16 cols
  // identical) — same row layout as acc, so normalization is per-lane.
  const int bb = bh >> 4, hh = bh & 15;
#pragma unroll
  for (int s = 0; s < 4; ++s) {
#pragma unroll
    for (int r = 0; r < 4; ++r) {
      const int qq = g * 4 + r;
      const float inv = 1.f / fmaxf(accl[s][r], 1e-30f);
      const int ti = q0 + wave * 64 + s * 16 + qq;
      u16* dst = AO + (((size_t)bb * TSEQ + ti) * NH + hh) * DH + lr;
#pragma unroll
      for (int dn = 0; dn < 4; ++dn)
        dst[dn * 16] = f2bf(acc[s][dn][r] * inv);
    }
  }
}

// ---------------------------------------------------------------------------
// Kernel 3: output projection  out = AO @ Wo^T + bo  (BK=64 two-buffer).
// Raw-Wo read when flag=1.
// ---------------------------------------------------------------------------
__global__ __launch_bounds__(256) void out_gemm(
    const int* __restrict__ flag_p,
    const u16* __restrict__ A, const u16* __restrict__ W,
    const void* __restrict__ wo_r,
    const void* __restrict__ bias_raw, void* __restrict__ outp)
{
  __shared__ __align__(16) u16 As[2 * 128 * 32];
  __shared__ __align__(16) u16 Bs[2 * 128 * 32];
  const int flag = *flag_p;
  const u16* __restrict__ Wm = flag ? (const u16*)wo_r : W;
  const int t = threadIdx.x;
  const int m0 = blockIdx.x * 128;
  const int n0 = blockIdx.y * 128;
  const int wave = t >> 6, lane = t & 63;
  const int wm = (wave >> 1) * 64, wn = (wave & 1) * 64;
  const int lr = lane & 15, kg = (lane >> 4) * 8;

  const int srow0 = t >> 2, skc = (t & 3) * 8;
  const int srow1 = srow0 + 64;
  const u16* a0 = A + (size_t)(m0 + srow0) * D_MODEL + skc;
  const u16* a1 = A + (size_t)(m0 + srow1) * D_MODEL + skc;
  const u16* b0 = Wm + (size_t)(n0 + srow0) * D_MODEL + skc;
  const u16* b1 = Wm + (size_t)(n0 + srow1) * D_MODEL + skc;

  f32x4 acc[4][4] = {};

  for (int kt = 0; kt < D_MODEL / 64; ++kt) {
    gl_lds16(a0,      &As[t * 8]);
    gl_lds16(a1,      &As[(t + 256) * 8]);
    gl_lds16(a0 + 32, &As[4096 + t * 8]);
    gl_lds16(a1 + 32, &As[4096 + (t + 256) * 8]);
    gl_lds16(b0,      &Bs[t * 8]);
    gl_lds16(b1,      &Bs[(t + 256) * 8]);
    gl_lds16(b0 + 32, &Bs[4096 + t * 8]);
    gl_lds16(b1 + 32, &Bs[4096 + (t + 256) * 8]);
    a0 += 64; a1 += 64; b0 += 64; b1 += 64;
    __syncthreads();
#pragma unroll
    for (int h = 0; h < 2; ++h) {
      bf16x8 af[4], bfr[4];
#pragma unroll
      for (int i = 0; i < 4; ++i)
        af[i] = *(const bf16x8*)&As[h * 4096 + (wm + i * 16 + lr) * 32 + kg];
#pragma unroll
      for (int j = 0; j < 4; ++j)
        bfr[j] = *(const bf16x8*)&Bs[h * 4096 + (wn + j * 16 + lr) * 32 + kg];
#pragma unroll
      for (int i = 0; i < 4; ++i)
#pragma unroll
        for (int j = 0; j < 4; ++j)
          acc[i][j] = __builtin_amdgcn_mfma_f32_16x16x32_bf16(af[i], bfr[j], acc[i][j], 0, 0, 0);
    }
    __syncthreads();
  }

#pragma unroll
  for (int j = 0; j < 4; ++j) {
    const int colg = n0 + wn + j * 16 + lr;
    const float bv = flag ? bf2f(((const u16*)bias_raw)[colg])
                          : ((const float*)bias_raw)[colg];
#pragma unroll
    for (int i = 0; i < 4; ++i) {
      const int rowg = m0 + wm + i * 16 + ((lane >> 4) << 2);
      if (flag) {
        u16* dst = (u16*)outp + (size_t)rowg * D_MODEL + colg;
#pragma unroll
        for (int r = 0; r < 4; ++r)
          dst[(size_t)r * D_MODEL] = f2bf(acc[i][j][r] + bv);
      } else {
        float* dst = (float*)outp + (size_t)rowg * D_MODEL + colg;
#pragma unroll
        for (int r = 0; r < 4; ++r)
          dst[(size_t)r * D_MODEL] = acc[i][j][r] + bv;
      }
    }
  }
}

extern "C" void kernel_launch(void* const* d_in, const int* in_sizes, int n_in,
                              void* d_out, int out_size, void* d_ws, size_t ws_size,
                              hipStream_t stream) {
  const void* x  = d_in[0];
  const void* wq = d_in[1];
  const void* wk = d_in[2];
  const void* wv = d_in[3];
  const void* wo = d_in[4];
  const void* bo = d_in[5];
  u16* dout = (u16*)d_out;

  // ws: [flag 16B][Wq][Wk][Wv][Wo bf16, 2MiB ea][K][VT][AO 16MiB ea]
  int* flag = (int*)d_ws;
  u16* wqb = (u16*)d_ws + 8;
  u16* wkb = wqb + WSZ;
  u16* wvb = wkb + WSZ;
  u16* wob = wvb + WSZ;
  u16* kk  = wob + WSZ;
  u16* vt  = kk + NQ;
  u16* ao  = vt + NQ;

  detect_dtype<<<1, 256, 0, stream>>>((const u32*)wq, flag);

  dim3 gc(NQ / (256 * 8), 5);
  convert_inputs<<<gc, dim3(256), 0, stream>>>(
      x, wq, wk, wv, wo, dout, wqb, wkb, wvb, wob, flag);

  dim3 g1(MTOT / 256, D_MODEL / 128, 1);
  qkv_gemm<<<g1, dim3(512), 0, stream>>>(
      flag, (const u16*)x, dout, wqb, wkb, wvb, wq, wk, wv, kk, vt);

  dim3 g2(BATCH * NH, TSEQ / 256, 1);
  flash_attn<<<g2, dim3(256), 0, stream>>>(flag, dout, kk, vt, ao);

  dim3 g3(MTOT / 128, D_MODEL / 128, 1);
  out_gemm<<<g3, dim3(256), 0, stream>>>(flag, ao, wob, wo, bo, d_out);
}

// Round 13
// 266.306 us; speedup vs baseline: 1.0307x; 1.0307x over previous
//
#include <hip/hip_runtime.h>
#include <stdint.h>

#define D_MODEL 1024
#define NH 16
#define DH 64
#define TSEQ 2048
#define BATCH 4
#define MTOT (BATCH*TSEQ)
#define NQ (MTOT*D_MODEL)      // elements in Q/K/VT/AO and in x
#define WSZ (D_MODEL*D_MODEL)  // elements in each weight matrix
// SCALE * log2(e), pre-folded into Q at the qkv epilogue
#define QSCALE 0.18033688f

typedef __attribute__((ext_vector_type(8))) short bf16x8;
typedef __attribute__((ext_vector_type(8))) unsigned short u16x8;
typedef __attribute__((ext_vector_type(4))) float f32x4;
typedef __attribute__((ext_vector_type(2))) float f32x2;
typedef unsigned short u16;
typedef unsigned int u32;

__device__ __forceinline__ void gl_lds16(const void* g, void* l) {
  __builtin_amdgcn_global_load_lds(
      (__attribute__((address_space(1))) void*)g,
      (__attribute__((address_space(3))) void*)l, 16, 0, 0);
}
__device__ __forceinline__ u16 f2bf(float f) {
  u32 u = __builtin_bit_cast(u32, f);
  u = u + 0x7fffu + ((u >> 16) & 1u);
  return (u16)(u >> 16);
}
__device__ __forceinline__ float bf2f(u16 b) {
  u32 u = ((u32)b) << 16;
  return __builtin_bit_cast(float, u);
}

// ---------------------------------------------------------------------------
// Fused raw exp2 + bf16 pack, hazards controlled IN-ASM (round-4 verified).
// Round-2 lesson: TRANS results consumed by a SEPARATE inline-asm within the
// hazard window gave wrong numerics; one asm block with 4 back-to-back exps
// + s_nop 1 before the packs is safe.
// ROUND-12 lesson: qkv 256-row tile (1 block/CU) neutral-negative — lost
// cross-block overlap canceled the bytes/MFMA gain. r6 128-tile restored.
// Cross-container noise: identical flash code measured 90.5 vs 97.5 us —
// per-kernel noise ~±4 us; sub-5 us cross-round deltas are unreadable.
// ---------------------------------------------------------------------------
__device__ __forceinline__ void exp2pk4(const f32x4 s, float& e0, float& e1,
                                        float& e2, float& e3, u32& pk01,
                                        u32& pk23) {
  asm("v_exp_f32 %0, %6\n\t"
      "v_exp_f32 %1, %7\n\t"
      "v_exp_f32 %2, %8\n\t"
      "v_exp_f32 %3, %9\n\t"
      "s_nop 1\n\t"
      "v_cvt_pk_bf16_f32 %4, %0, %1\n\t"
      "v_cvt_pk_bf16_f32 %5, %2, %3"
      : "=&v"(e0), "=&v"(e1), "=&v"(e2), "=&v"(e3), "=&v"(pk01), "=&v"(pk23)
      : "v"(s[0]), "v"(s[1]), "v"(s[2]), "v"(s[3]));
}

// ---------------------------------------------------------------------------
// Kernel 0: input dtype detection (1 = bf16, 0 = fp32).
// ---------------------------------------------------------------------------
__global__ __launch_bounds__(256) void detect_dtype(
    const u32* __restrict__ wq_raw, int* __restrict__ flag)
{
  __shared__ int cnt;
  if (threadIdx.x == 0) cnt = 0;
  __syncthreads();
  int c = 0;
  for (int i = threadIdx.x; i < 2048; i += 256) {
    const u32 e = (wq_raw[i] >> 7) & 0xFFu;
    if (e >= 90u && e <= 126u) ++c;
  }
  atomicAdd(&cnt, c);
  __syncthreads();
  if (threadIdx.x == 0) *flag = (cnt > 1024) ? 1 : 0;
}

// ---------------------------------------------------------------------------
// Kernel 0b: convert inputs to bf16 — fp32 path ONLY (flag=1 early-exits;
// consumers read raw pointers directly).
// ---------------------------------------------------------------------------
__global__ __launch_bounds__(256) void convert_inputs(
    const void* __restrict__ x, const void* __restrict__ wq,
    const void* __restrict__ wk, const void* __restrict__ wv,
    const void* __restrict__ wo,
    u16* __restrict__ xb, u16* __restrict__ wqb, u16* __restrict__ wkb,
    u16* __restrict__ wvb, u16* __restrict__ wob,
    const int* __restrict__ flag_p)
{
  if (*flag_p) return;  // bf16 inputs: consumers read raw pointers directly
  const int seg = blockIdx.y;
  const void* src; u16* dst; int n;
  switch (seg) {
    case 0:  src = x;  dst = xb;  n = NQ;  break;
    case 1:  src = wq; dst = wqb; n = WSZ; break;
    case 2:  src = wk; dst = wkb; n = WSZ; break;
    case 3:  src = wv; dst = wvb; n = WSZ; break;
    default: src = wo; dst = wob; n = WSZ; break;
  }
  const int idx = (blockIdx.x * 256 + threadIdx.x) * 8;
  if (idx >= n) return;
  const float4 f0 = *(const float4*)((const float*)src + idx);
  const float4 f1 = *(const float4*)((const float*)src + idx + 4);
  union { u16 s[8]; u16x8 v; } u;
  u.s[0] = f2bf(f0.x); u.s[1] = f2bf(f0.y); u.s[2] = f2bf(f0.z); u.s[3] = f2bf(f0.w);
  u.s[4] = f2bf(f1.x); u.s[5] = f2bf(f1.y); u.s[6] = f2bf(f1.z); u.s[7] = f2bf(f1.w);
  *(u16x8*)(dst + idx) = u.v;
}

// ---------------------------------------------------------------------------
// Kernel 1: FUSED QKV projection — EXACT round-6 version (green, fastest
// measured). One K-loop (BK=64 via two BK=32 halves per barrier-pair) stages
// the A-tile (X) ONCE plus all three B-tiles; 96 MFMA per barrier-pair with
// shared A-fragments. K-output via swapped operands mfma(bk, af) -> D[d][t]
// for 8B vectorized stores.
// Outputs: Q^T [B,H,64,T] (pre-scaled), K [B,H,T,64], V^T [B,H,64,T].
// ---------------------------------------------------------------------------
__global__ __launch_bounds__(256, 2) void qkv_gemm(
    const int* __restrict__ flag_p, const u16* __restrict__ x_raw,
    u16* __restrict__ dout,
    const u16* __restrict__ Wq, const u16* __restrict__ Wk,
    const u16* __restrict__ Wv,
    const void* __restrict__ wq_r, const void* __restrict__ wk_r,
    const void* __restrict__ wv_r,
    u16* __restrict__ Ko, u16* __restrict__ VTo)
{
  __shared__ __align__(16) u16 As [2 * 128 * 32];
  __shared__ __align__(16) u16 Bqs[2 * 128 * 32];
  __shared__ __align__(16) u16 Bks[2 * 128 * 32];
  __shared__ __align__(16) u16 Bvs[2 * 128 * 32];
  const int flag = *flag_p;
  const u16* __restrict__ X  = flag ? x_raw : dout;  // converted x in dout low
  u16* __restrict__ QTo = flag ? dout : dout + NQ;
  const u16* __restrict__ WQ = flag ? (const u16*)wq_r : Wq;
  const u16* __restrict__ WK = flag ? (const u16*)wk_r : Wk;
  const u16* __restrict__ WV = flag ? (const u16*)wv_r : Wv;
  const int t = threadIdx.x;
  const int m0 = blockIdx.x * 128;
  const int n0 = blockIdx.y * 128;
  const int wave = t >> 6, lane = t & 63;
  const int wm = (wave >> 1) * 64, wn = (wave & 1) * 64;
  const int lr = lane & 15, g = lane >> 4, kg = g * 8;

  const int srow0 = t >> 2, skc = (t & 3) * 8;
  const int srow1 = srow0 + 64;
  const u16* a0 = X  + (size_t)(m0 + srow0) * D_MODEL + skc;
  const u16* a1 = X  + (size_t)(m0 + srow1) * D_MODEL + skc;
  const u16* q0p = WQ + (size_t)(n0 + srow0) * D_MODEL + skc;
  const u16* q1p = WQ + (size_t)(n0 + srow1) * D_MODEL + skc;
  const u16* k0p = WK + (size_t)(n0 + srow0) * D_MODEL + skc;
  const u16* k1p = WK + (size_t)(n0 + srow1) * D_MODEL + skc;
  const u16* v0p = WV + (size_t)(n0 + srow0) * D_MODEL + skc;
  const u16* v1p = WV + (size_t)(n0 + srow1) * D_MODEL + skc;

  f32x4 accq[4][4] = {};  // [i=m][j=n]
  f32x4 acck[4][4] = {};  // [j=n][i=m]  (swapped-operand output D[d][t])
  f32x4 accv[4][4] = {};  // [i=m][j=n]

  for (int kt = 0; kt < D_MODEL / 64; ++kt) {
    gl_lds16(a0,       &As [t * 8]);
    gl_lds16(a1,       &As [(t + 256) * 8]);
    gl_lds16(a0 + 32,  &As [4096 + t * 8]);
    gl_lds16(a1 + 32,  &As [4096 + (t + 256) * 8]);
    gl_lds16(q0p,      &Bqs[t * 8]);
    gl_lds16(q1p,      &Bqs[(t + 256) * 8]);
    gl_lds16(q0p + 32, &Bqs[4096 + t * 8]);
    gl_lds16(q1p + 32, &Bqs[4096 + (t + 256) * 8]);
    gl_lds16(k0p,      &Bks[t * 8]);
    gl_lds16(k1p,      &Bks[(t + 256) * 8]);
    gl_lds16(k0p + 32, &Bks[4096 + t * 8]);
    gl_lds16(k1p + 32, &Bks[4096 + (t + 256) * 8]);
    gl_lds16(v0p,      &Bvs[t * 8]);
    gl_lds16(v1p,      &Bvs[(t + 256) * 8]);
    gl_lds16(v0p + 32, &Bvs[4096 + t * 8]);
    gl_lds16(v1p + 32, &Bvs[4096 + (t + 256) * 8]);
    a0 += 64; a1 += 64; q0p += 64; q1p += 64;
    k0p += 64; k1p += 64; v0p += 64; v1p += 64;
    __syncthreads();
#pragma unroll
    for (int h = 0; h < 2; ++h) {
      bf16x8 af[4], bfr[4];
#pragma unroll
      for (int i = 0; i < 4; ++i)
        af[i] = *(const bf16x8*)&As[h * 4096 + (wm + i * 16 + lr) * 32 + kg];
      // Q
#pragma unroll
      for (int j = 0; j < 4; ++j)
        bfr[j] = *(const bf16x8*)&Bqs[h * 4096 + (wn + j * 16 + lr) * 32 + kg];
#pragma unroll
      for (int i = 0; i < 4; ++i)
#pragma unroll
        for (int j = 0; j < 4; ++j)
          accq[i][j] = __builtin_amdgcn_mfma_f32_16x16x32_bf16(af[i], bfr[j], accq[i][j], 0, 0, 0);
      // K (swapped: A = W-fragment -> rows = d, cols = t)
#pragma unroll
      for (int j = 0; j < 4; ++j)
        bfr[j] = *(const bf16x8*)&Bks[h * 4096 + (wn + j * 16 + lr) * 32 + kg];
#pragma unroll
      for (int j = 0; j < 4; ++j)
#pragma unroll
        for (int i = 0; i < 4; ++i)
          acck[j][i] = __builtin_amdgcn_mfma_f32_16x16x32_bf16(bfr[j], af[i], acck[j][i], 0, 0, 0);
      // V
#pragma unroll
      for (int j = 0; j < 4; ++j)
        bfr[j] = *(const bf16x8*)&Bvs[h * 4096 + (wn + j * 16 + lr) * 32 + kg];
#pragma unroll
      for (int i = 0; i < 4; ++i)
#pragma unroll
        for (int j = 0; j < 4; ++j)
          accv[i][j] = __builtin_amdgcn_mfma_f32_16x16x32_bf16(af[i], bfr[j], accv[i][j], 0, 0, 0);
    }
    __syncthreads();
  }

  // C/D layout: col = lane&15, row = (lane>>4)*4 + reg
  const int bidx = m0 >> 11;
  // --- Q^T (scaled) and V^T: [B,H,64,T], vectorized 8B stores along t ---
#pragma unroll
  for (int zz = 0; zz < 2; ++zz) {
    u16* O = zz ? VTo : QTo;
    const float sc = zz ? 1.0f : QSCALE;
#pragma unroll
    for (int i = 0; i < 4; ++i) {
      const int rowg = m0 + wm + i * 16 + (g << 2);
      const int tq = rowg & (TSEQ - 1);  // multiple of 4 -> 8B aligned
#pragma unroll
      for (int j = 0; j < 4; ++j) {
        const int colg = n0 + wn + j * 16 + lr;
        const int h = colg >> 6, d = colg & 63;
        const f32x4 a = zz ? accv[i][j] : accq[i][j];
        union { u16 s[4]; uint2 v; } u;
#pragma unroll
        for (int r = 0; r < 4; ++r) u.s[r] = f2bf(a[r] * sc);
        *(uint2*)&O[((size_t)(bidx * NH + h) * DH + d) * TSEQ + tq] = u.v;
      }
    }
  }
  // --- K: [B,H,T,64]. Swapped output D[d][t]: col=lr -> t, row=g*4+r -> d.
  //     reg r walks d => one 8B store per (j,i). ---
#pragma unroll
  for (int j = 0; j < 4; ++j) {
    const int dg = n0 + wn + j * 16 + (g << 2);  // d-global base (r adds 0..3)
    const int hh = dg >> 6, d0 = dg & 63;        // head fixed over r
#pragma unroll
    for (int i = 0; i < 4; ++i) {
      const int tg = m0 + wm + i * 16 + lr;
      const int tq = tg & (TSEQ - 1);
      union { u16 s[4]; uint2 v; } u;
#pragma unroll
      for (int r = 0; r < 4; ++r) u.s[r] = f2bf(acck[j][i][r]);
      *(uint2*)&Ko[((size_t)(bidx * NH + hh) * TSEQ + tq) * DH + d0] = u.v;
    }
  }
}

// ---------------------------------------------------------------------------
// Kernel 2: flash attention — EXACT round-11 version (green, best measured
// 90.5 us, MfmaUtil 35). Round-6 structure + lsum-via-MFMA (denominator =
// row-sum of the SAME rounded bf16 P via mfma(P_frag, ones)).
// ---------------------------------------------------------------------------
__global__ __launch_bounds__(256) void flash_attn(
    const int* __restrict__ flag_p, const u16* __restrict__ dout,
    const u16* __restrict__ K, const u16* __restrict__ VT,
    u16* __restrict__ AO)
{
  __shared__ __align__(16) u16 Ks[2][2 * 64 * 32];  // [buf][half][64 keys][32 d]
  __shared__ __align__(16) u16 Vs[2][2 * 64 * 32];  // [buf][half][64 d][32 keys]
  __shared__ __align__(16) u16 Ps[4 * 64 * 72];     // per-wave [64 q][64+8 keys]
  const int flag = *flag_p;
  const u16* __restrict__ QT = flag ? dout : dout + NQ;
  const int t = threadIdx.x;
  const int wave = t >> 6, lane = t & 63;
  const int lr = lane & 15, g = lane >> 4, kg = g * 8;
  const int bh = blockIdx.x;          // fastest grid dim -> XCD = bh % 8
  const int q0 = blockIdx.y * 256;
  const u16* __restrict__ QTh = QT + (size_t)bh * DH * TSEQ;  // [64 d][T]
  const u16* __restrict__ Kh = K + (size_t)bh * TSEQ * DH;
  const u16* __restrict__ Vh = VT + (size_t)bh * DH * TSEQ;

  // 8 Q B-fragments per wave: q-sets s=0..3 (16 q each), d-halves 0/1.
  const int qi = q0 + wave * 64 + lr;
  bf16x8 qf[8];
#pragma unroll
  for (int s = 0; s < 4; ++s) {
    union { u16 v[8]; bf16x8 b; } u0, u1;
#pragma unroll
    for (int j = 0; j < 8; ++j) {
      u0.v[j] = QTh[(size_t)(kg + j) * TSEQ + qi + s * 16];
      u1.v[j] = QTh[(size_t)(32 + kg + j) * TSEQ + qi + s * 16];
    }
    qf[s * 2] = u0.b; qf[s * 2 + 1] = u1.b;
  }

  // ones fragment for the lsum MFMA (bf16 1.0 = 0x3F80)
  union { u32 w[4]; bf16x8 b; } onesu;
  onesu.w[0] = onesu.w[1] = onesu.w[2] = onesu.w[3] = 0x3F803F80u;
  const bf16x8 vones = onesu.b;

  f32x4 acc[4][4] = {};                 // [set][dn]
  f32x4 accl[4] = {};                   // [set] row-sums of P (lsum)

  const int srow = t >> 2, skc = (t & 3) * 8;
  const u16* kb = Kh + (size_t)srow * DH + skc;
  const u16* vb = Vh + (size_t)srow * TSEQ + skc;
  u16* const pw = &Ps[wave * 64 * 72];  // q-set s at rows s*16..s*16+15

  // prologue: prefetch tile 0 into buffer 0
  gl_lds16(kb,      &Ks[0][t * 8]);          // keys, d 0..31
  gl_lds16(kb + 32, &Ks[0][(t + 256) * 8]);  // keys, d 32..63
  gl_lds16(vb,      &Vs[0][t * 8]);          // [d][keys 0..31]
  gl_lds16(vb + 32, &Vs[0][(t + 256) * 8]);  // [d][keys 32..63]
  kb += 64 * DH; vb += 64;

  int cur = 0;
  for (int j0 = 0; j0 < TSEQ; j0 += 64) {
    // single barrier per tile: drains cur-buf loads (issued a full tile ago)
    // and guarantees everyone is done reading buf^1 before we overwrite it.
    __syncthreads();
    if (j0 + 64 < TSEQ) {
      gl_lds16(kb,      &Ks[cur ^ 1][t * 8]);
      gl_lds16(kb + 32, &Ks[cur ^ 1][(t + 256) * 8]);
      gl_lds16(vb,      &Vs[cur ^ 1][t * 8]);
      gl_lds16(vb + 32, &Vs[cur ^ 1][(t + 256) * 8]);
      kb += 64 * DH; vb += 64;
    }
    const u16* __restrict__ Kc = Ks[cur];
    const u16* __restrict__ Vc = Vs[cur];

    // --- QK key-rows 0..31 (jn = 0,1) ---
#pragma unroll
    for (int jn = 0; jn < 2; ++jn) {
      const bf16x8 kf0 = *(const bf16x8*)&Kc[(jn * 16 + lr) * 32 + kg];
      const bf16x8 kf1 = *(const bf16x8*)&Kc[2048 + (jn * 16 + lr) * 32 + kg];
#pragma unroll
      for (int s = 0; s < 4; ++s) {
        f32x4 sS = {};
        sS = __builtin_amdgcn_mfma_f32_16x16x32_bf16(kf0, qf[s * 2],     sS, 0, 0, 0);
        sS = __builtin_amdgcn_mfma_f32_16x16x32_bf16(kf1, qf[s * 2 + 1], sS, 0, 0, 0);
        float e0, e1, e2, e3;
        uint2 w;
        exp2pk4(sS, e0, e1, e2, e3, w.x, w.y);
        *(uint2*)&pw[s * 16 * 72 + lr * 72 + jn * 16 + g * 4] = w;
      }
    }

    // pf0 (keys 0..31) issued now: in-order DS -> completes after the jn0/1
    // writes (same region) but does NOT wait on the jn2/3 writes below.
    bf16x8 pf0[4];
#pragma unroll
    for (int s = 0; s < 4; ++s)
      pf0[s] = *(const bf16x8*)&pw[s * 16 * 72 + lr * 72 + kg];

    // --- QK key-rows 32..63 (jn = 2,3): VALU here covers pf0 DS latency ---
#pragma unroll
    for (int jn = 2; jn < 4; ++jn) {
      const bf16x8 kf0 = *(const bf16x8*)&Kc[(jn * 16 + lr) * 32 + kg];
      const bf16x8 kf1 = *(const bf16x8*)&Kc[2048 + (jn * 16 + lr) * 32 + kg];
#pragma unroll
      for (int s = 0; s < 4; ++s) {
        f32x4 sS = {};
        sS = __builtin_amdgcn_mfma_f32_16x16x32_bf16(kf0, qf[s * 2],     sS, 0, 0, 0);
        sS = __builtin_amdgcn_mfma_f32_16x16x32_bf16(kf1, qf[s * 2 + 1], sS, 0, 0, 0);
        float e0, e1, e2, e3;
        uint2 w;
        exp2pk4(sS, e0, e1, e2, e3, w.x, w.y);
        *(uint2*)&pw[s * 16 * 72 + lr * 72 + jn * 16 + g * 4] = w;
      }
    }

    // --- PV key-half 0 (+ lsum row-sum via ones-MFMA) ---
#pragma unroll
    for (int dn = 0; dn < 4; ++dn) {
      const bf16x8 vf0 = *(const bf16x8*)&Vc[(dn * 16 + lr) * 32 + kg];
#pragma unroll
      for (int s = 0; s < 4; ++s)
        acc[s][dn] = __builtin_amdgcn_mfma_f32_16x16x32_bf16(pf0[s], vf0, acc[s][dn], 0, 0, 0);
    }
#pragma unroll
    for (int s = 0; s < 4; ++s)
      accl[s] = __builtin_amdgcn_mfma_f32_16x16x32_bf16(pf0[s], vones, accl[s], 0, 0, 0);

    // pf1 (keys 32..63), then PV key-half 1 (+ lsum)
    bf16x8 pf1[4];
#pragma unroll
    for (int s = 0; s < 4; ++s)
      pf1[s] = *(const bf16x8*)&pw[s * 16 * 72 + lr * 72 + 32 + kg];
#pragma unroll
    for (int dn = 0; dn < 4; ++dn) {
      const bf16x8 vf1 = *(const bf16x8*)&Vc[2048 + (dn * 16 + lr) * 32 + kg];
#pragma unroll
      for (int s = 0; s < 4; ++s)
        acc[s][dn] = __builtin_amdgcn_mfma_f32_16x16x32_bf16(pf1[s], vf1, acc[s][dn], 0, 0, 0);
    }
#pragma unroll
    for (int s = 0; s < 4; ++s)
      accl[s] = __builtin_amdgcn_mfma_f32_16x16x32_bf16(pf1[s], vones, accl[s], 0, 0, 0);
    cur ^= 1;
  }

  // Epilogue: accl[s][r] holds lsum for q-row g*4+r of set s (all 16 cols
  // identical) — same row layout as acc, so normalization is per-lane.
  const int bb = bh >> 4, hh = bh & 15;
#pragma unroll
  for (int s = 0; s < 4; ++s) {
#pragma unroll
    for (int r = 0; r < 4; ++r) {
      const int qq = g * 4 + r;
      const float inv = 1.f / fmaxf(accl[s][r], 1e-30f);
      const int ti = q0 + wave * 64 + s * 16 + qq;
      u16* dst = AO + (((size_t)bb * TSEQ + ti) * NH + hh) * DH + lr;
#pragma unroll
      for (int dn = 0; dn < 4; ++dn)
        dst[dn * 16] = f2bf(acc[s][dn][r] * inv);
    }
  }
}

// ---------------------------------------------------------------------------
// Kernel 3: output projection  out = AO @ Wo^T + bo  (BK=64 two-buffer).
// ROUND-13: swapped-operand accumulation acc[j][i] = mfma(bfr[j], af[i]) ->
// D col (lr) = output row m, D row (g*4+r) = output col n: reg r walks n,
// so the C-write is one 16B float4 (or 8B bf16x4) store per (j,i) with a
// float4 bias load per j — 4x fewer epilogue stores. Same trick verified in
// qkv's K-output since r6. Raw-Wo read when flag=1.
// ---------------------------------------------------------------------------
__global__ __launch_bounds__(256) void out_gemm(
    const int* __restrict__ flag_p,
    const u16* __restrict__ A, const u16* __restrict__ W,
    const void* __restrict__ wo_r,
    const void* __restrict__ bias_raw, void* __restrict__ outp)
{
  __shared__ __align__(16) u16 As[2 * 128 * 32];
  __shared__ __align__(16) u16 Bs[2 * 128 * 32];
  const int flag = *flag_p;
  const u16* __restrict__ Wm = flag ? (const u16*)wo_r : W;
  const int t = threadIdx.x;
  const int m0 = blockIdx.x * 128;
  const int n0 = blockIdx.y * 128;
  const int wave = t >> 6, lane = t & 63;
  const int wm = (wave >> 1) * 64, wn = (wave & 1) * 64;
  const int lr = lane & 15, g = lane >> 4, kg = g * 8;

  const int srow0 = t >> 2, skc = (t & 3) * 8;
  const int srow1 = srow0 + 64;
  const u16* a0 = A + (size_t)(m0 + srow0) * D_MODEL + skc;
  const u16* a1 = A + (size_t)(m0 + srow1) * D_MODEL + skc;
  const u16* b0 = Wm + (size_t)(n0 + srow0) * D_MODEL + skc;
  const u16* b1 = Wm + (size_t)(n0 + srow1) * D_MODEL + skc;

  f32x4 acc[4][4] = {};  // [j=n][i=m] swapped-operand

  for (int kt = 0; kt < D_MODEL / 64; ++kt) {
    gl_lds16(a0,      &As[t * 8]);
    gl_lds16(a1,      &As[(t + 256) * 8]);
    gl_lds16(a0 + 32, &As[4096 + t * 8]);
    gl_lds16(a1 + 32, &As[4096 + (t + 256) * 8]);
    gl_lds16(b0,      &Bs[t * 8]);
    gl_lds16(b1,      &Bs[(t + 256) * 8]);
    gl_lds16(b0 + 32, &Bs[4096 + t * 8]);
    gl_lds16(b1 + 32, &Bs[4096 + (t + 256) * 8]);
    a0 += 64; a1 += 64; b0 += 64; b1 += 64;
    __syncthreads();
#pragma unroll
    for (int h = 0; h < 2; ++h) {
      bf16x8 af[4], bfr[4];
#pragma unroll
      for (int i = 0; i < 4; ++i)
        af[i] = *(const bf16x8*)&As[h * 4096 + (wm + i * 16 + lr) * 32 + kg];
#pragma unroll
      for (int j = 0; j < 4; ++j)
        bfr[j] = *(const bf16x8*)&Bs[h * 4096 + (wn + j * 16 + lr) * 32 + kg];
#pragma unroll
      for (int j = 0; j < 4; ++j)
#pragma unroll
        for (int i = 0; i < 4; ++i)
          acc[j][i] = __builtin_amdgcn_mfma_f32_16x16x32_bf16(bfr[j], af[i], acc[j][i], 0, 0, 0);
    }
    __syncthreads();
  }

  // Swapped C/D: for (j,i): out row = m0+wm+i*16+lr, col = n0+wn+j*16+g*4+r.
#pragma unroll
  for (int j = 0; j < 4; ++j) {
    const int colg = n0 + wn + j * 16 + (g << 2);  // r adds 0..3
    float bv[4];
    if (flag) {
#pragma unroll
      for (int r = 0; r < 4; ++r)
        bv[r] = bf2f(((const u16*)bias_raw)[colg + r]);
    } else {
      const float4 b4 = *(const float4*)((const float*)bias_raw + colg);
      bv[0] = b4.x; bv[1] = b4.y; bv[2] = b4.z; bv[3] = b4.w;
    }
#pragma unroll
    for (int i = 0; i < 4; ++i) {
      const int rowg = m0 + wm + i * 16 + lr;
      if (flag) {
        union { u16 s[4]; uint2 v; } u;
#pragma unroll
        for (int r = 0; r < 4; ++r) u.s[r] = f2bf(acc[j][i][r] + bv[r]);
        *(uint2*)((u16*)outp + (size_t)rowg * D_MODEL + colg) = u.v;
      } else {
        float4 o;
        o.x = acc[j][i][0] + bv[0]; o.y = acc[j][i][1] + bv[1];
        o.z = acc[j][i][2] + bv[2]; o.w = acc[j][i][3] + bv[3];
        *(float4*)((float*)outp + (size_t)rowg * D_MODEL + colg) = o;
      }
    }
  }
}

extern "C" void kernel_launch(void* const* d_in, const int* in_sizes, int n_in,
                              void* d_out, int out_size, void* d_ws, size_t ws_size,
                              hipStream_t stream) {
  const void* x  = d_in[0];
  const void* wq = d_in[1];
  const void* wk = d_in[2];
  const void* wv = d_in[3];
  const void* wo = d_in[4];
  const void* bo = d_in[5];
  u16* dout = (u16*)d_out;

  // ws: [flag 16B][Wq][Wk][Wv][Wo bf16, 2MiB ea][K][VT][AO 16MiB ea]
  int* flag = (int*)d_ws;
  u16* wqb = (u16*)d_ws + 8;
  u16* wkb = wqb + WSZ;
  u16* wvb = wkb + WSZ;
  u16* wob = wvb + WSZ;
  u16* kk  = wob + WSZ;
  u16* vt  = kk + NQ;
  u16* ao  = vt + NQ;

  detect_dtype<<<1, 256, 0, stream>>>((const u32*)wq, flag);

  dim3 gc(NQ / (256 * 8), 5);
  convert_inputs<<<gc, dim3(256), 0, stream>>>(
      x, wq, wk, wv, wo, dout, wqb, wkb, wvb, wob, flag);

  dim3 g1(MTOT / 128, D_MODEL / 128, 1);
  qkv_gemm<<<g1, dim3(256), 0, stream>>>(
      flag, (const u16*)x, dout, wqb, wkb, wvb, wq, wk, wv, kk, vt);

  dim3 g2(BATCH * NH, TSEQ / 256, 1);
  flash_attn<<<g2, dim3(256), 0, stream>>>(flag, dout, kk, vt, ao);

  dim3 g3(MTOT / 128, D_MODEL / 128, 1);
  out_gemm<<<g3, dim3(256), 0, stream>>>(flag, ao, wob, wo, bo, d_out);
}